// Round 13
// baseline (128.323 us; speedup 1.0000x reference)
//
#include <hip/hip_runtime.h>
#include <stdint.h>

typedef unsigned short u16;
typedef __attribute__((ext_vector_type(8))) short short8;
typedef __attribute__((ext_vector_type(4))) float f32x4;

#define NB    16
#define DIM   256
#define NTOK  1024

__device__ __forceinline__ u16 f2b(float f) {
    union { float f; uint32_t u; } v; v.f = f;
    uint32_t u = v.u;
    u += 0x7fffu + ((u >> 16) & 1u);
    return (u16)(u >> 16);
}
__device__ __forceinline__ float b2f(u16 h) {
    union { uint32_t u; float f; } v; v.u = ((uint32_t)h) << 16;
    return v.f;
}
__device__ __forceinline__ f32x4 mfma16(short8 a, short8 b, f32x4 c) {
    return __builtin_amdgcn_mfma_f32_16x16x32_bf16(a, b, c, 0, 0, 0);
}
__device__ __forceinline__ short8 ld8(const u16* p) {
    return *reinterpret_cast<const short8*>(p);
}
__device__ __forceinline__ void gl_lds(const u16* g, u16* l) {
    __builtin_amdgcn_global_load_lds((const __attribute__((address_space(1))) void*)g,
                                     (__attribute__((address_space(3))) void*)l, 16, 0, 0);
}

// ---------------- Kernel 1: pack x -> xbf + nodes; blocks >=1024 convert weights.
__global__ __launch_bounds__(256) void pack_kernel(const float* __restrict__ x,
                                                   u16* __restrict__ xbf,
                                                   u16* __restrict__ nodes,
                                                   const float* __restrict__ pw,
                                                   const float* __restrict__ w1,
                                                   const float* __restrict__ w2,
                                                   u16* __restrict__ wbf) {
    __shared__ float tile[64][67];
    int tid = threadIdx.x;
    int blk = blockIdx.x;
    if (blk >= 1024) {               // weight conversion: 96 blocks x 2048 elems
        int e = (blk - 1024) * 2048 + tid * 8;
        const float* s; int off;
        if (e < 65536)       { s = pw; off = e; }
        else if (e < 131072) { s = w1; off = e - 65536; }
        else                 { s = w2; off = e - 131072; }
        float4 f0 = *reinterpret_cast<const float4*>(s + off);
        float4 f1 = *reinterpret_cast<const float4*>(s + off + 4);
        ushort4 a, bb;
        a.x = f2b(f0.x); a.y = f2b(f0.y); a.z = f2b(f0.z); a.w = f2b(f0.w);
        bb.x = f2b(f1.x); bb.y = f2b(f1.y); bb.z = f2b(f1.z); bb.w = f2b(f1.w);
        *reinterpret_cast<ushort4*>(wbf + e)     = a;
        *reinterpret_cast<ushort4*>(wbf + e + 4) = bb;
        return;
    }
    int b  = blk >> 6;
    int t  = blk & 63;
    int c0 = (t >> 4) << 6;
    int n0 = (t & 15) << 6;
    const float* xb = x + (size_t)b * (DIM * NTOK);
    u16* xbb = xbf + (size_t)b * (DIM * NTOK);
#pragma unroll
    for (int i = 0; i < 4; i++) {
        int idx = i * 256 + tid;
        int cl = idx >> 4, nq = idx & 15;
        float4 f = *reinterpret_cast<const float4*>(xb + (size_t)(c0 + cl) * NTOK + n0 + nq * 4);
        tile[cl][nq * 4 + 0] = f.x;
        tile[cl][nq * 4 + 1] = f.y;
        tile[cl][nq * 4 + 2] = f.z;
        tile[cl][nq * 4 + 3] = f.w;
        ushort4 s;
        s.x = f2b(f.x); s.y = f2b(f.y); s.z = f2b(f.z); s.w = f2b(f.w);
        *reinterpret_cast<ushort4*>(xbb + (size_t)(c0 + cl) * NTOK + n0 + nq * 4) = s;
    }
    __syncthreads();
#pragma unroll
    for (int i = 0; i < 4; i++) {
        int idx = i * 256 + tid;
        int nl = idx >> 4, cq = idx & 15;
        ushort4 s;
        s.x = f2b(tile[cq * 4 + 0][nl]);
        s.y = f2b(tile[cq * 4 + 1][nl]);
        s.z = f2b(tile[cq * 4 + 2][nl]);
        s.w = f2b(tile[cq * 4 + 3][nl]);
        *reinterpret_cast<ushort4*>(nodes + (size_t)(b * NTOK + n0 + nl) * DIM + c0 + cq * 4) = s;
    }
}

// ---------------- Kernel 2: q = nodes @ proj_w^T + proj_b. 4-way column split.
__global__ __launch_bounds__(256) void proj_kernel(const u16* __restrict__ nodes,
                                                   const u16* __restrict__ wbf,
                                                   const float* __restrict__ pb,
                                                   u16* __restrict__ qb) {
    int lane = threadIdx.x & 63;
    int w = threadIdx.x >> 6;
    int lo = lane & 15, hi = lane >> 4;
    int ch = blockIdx.x & 3;
    int row0 = (blockIdx.x >> 2) * 64 + w * 16;
    const u16* arow = nodes + (size_t)(row0 + lo) * DIM + hi * 8;
    f32x4 acc[4];
#pragma unroll
    for (int i = 0; i < 4; i++) acc[i] = (f32x4){0.f, 0.f, 0.f, 0.f};
#pragma unroll
    for (int t = 0; t < 8; t++) {
        short8 a = ld8(arow + t * 32);
#pragma unroll
        for (int nf = 0; nf < 4; nf++) {
            short8 bfr = ld8(wbf + ((ch * 4 + nf) * 16 + lo) * DIM + t * 32 + hi * 8);
            acc[nf] = mfma16(a, bfr, acc[nf]);
        }
    }
#pragma unroll
    for (int nf = 0; nf < 4; nf++) {
        int col = (ch * 4 + nf) * 16 + lo;
        float bias = pb[col];
#pragma unroll
        for (int r = 0; r < 4; r++) {
            int row = row0 + hi * 4 + r;
            qb[(size_t)row * DIM + col] = f2b(acc[nf][r] + bias);
        }
    }
}

// ---------------- Kernel 3: P = exp2(Q Q^T * C1 - 12) bf16. 128x128 tile, K=256.
// grid = 64 tiles x nb batches (2 blocks/CU at nb=8). Proven swizzles/fragments.
__global__ __launch_bounds__(256, 2) void sgemm_kernel(const u16* __restrict__ qb,
                                                       u16* __restrict__ P,
                                                       int batch0, int bmask, int bshift) {
    __shared__ u16 tA[2][8192];   // [buf][128 rows x 64 k]  32 KB
    __shared__ u16 tB[2][8192];   // 32 KB
    int lane = threadIdx.x & 63;
    int w = threadIdx.x >> 6;
    int wm = w >> 1, wn = w & 1;
    int lo = lane & 15, hi = lane >> 4;
    int bb = batch0 + ((int)blockIdx.x & bmask);
    int rest = blockIdx.x >> bshift;
    int ti = rest & 7, tj = rest >> 3;
    const u16* qbb = qb + (size_t)bb * (NTOK * DIM);

    int aSrc[4], bSrc[4], dOff[4];
#pragma unroll
    for (int i = 0; i < 4; i++) {
        int idx = w * 4 + i;
        int arow = idx * 8 + (lane >> 3);
        int slot = (lane & 7) ^ (arow & 7);
        aSrc[i] = (ti * 128 + arow) * 256 + slot * 8;
        bSrc[i] = (tj * 128 + arow) * 256 + slot * 8;
        dOff[i] = idx * 512;
    }
    f32x4 acc[4][4];
#pragma unroll
    for (int i = 0; i < 4; i++)
#pragma unroll
        for (int j = 0; j < 4; j++) acc[i][j] = (f32x4){0.f, 0.f, 0.f, 0.f};

#pragma unroll
    for (int i = 0; i < 4; i++) {
        gl_lds(qbb + aSrc[i], &tA[0][dOff[i]]);
        gl_lds(qbb + bSrc[i], &tB[0][dOff[i]]);
    }
    __syncthreads();

    for (int kk = 0; kk < 4; kk++) {
        int buf = kk & 1;
        if (kk < 3) {
#pragma unroll
            for (int i = 0; i < 4; i++) {
                gl_lds(qbb + aSrc[i] + (kk + 1) * 64, &tA[buf ^ 1][dOff[i]]);
                gl_lds(qbb + bSrc[i] + (kk + 1) * 64, &tB[buf ^ 1][dOff[i]]);
            }
        }
        __builtin_amdgcn_s_setprio(1);
#pragma unroll
        for (int k0 = 0; k0 < 2; k0++) {
            int sl = ((k0 * 4 + hi) ^ (lo & 7)) * 8;
            short8 av[4], bv[4];
#pragma unroll
            for (int am = 0; am < 4; am++)
                av[am] = ld8(&tA[buf][(wm * 64 + am * 16 + lo) * 64 + sl]);
#pragma unroll
            for (int bn = 0; bn < 4; bn++)
                bv[bn] = ld8(&tB[buf][(wn * 64 + bn * 16 + lo) * 64 + sl]);
#pragma unroll
            for (int am = 0; am < 4; am++)
#pragma unroll
                for (int bn = 0; bn < 4; bn++)
                    acc[am][bn] = mfma16(av[am], bv[bn], acc[am][bn]);
        }
        __builtin_amdgcn_s_setprio(0);
        __syncthreads();
    }

    const float C1 = 0.0625f * 1.44269504f;
    u16* tP = &tA[0][0];   // 32 KB = 128 x 128 bf16, granule-swizzled
#pragma unroll
    for (int am = 0; am < 4; am++)
#pragma unroll
        for (int bn = 0; bn < 4; bn++)
#pragma unroll
            for (int r = 0; r < 4; r++) {
                float p = exp2f(acc[am][bn][r] * C1 - 12.f);
                int prow = wm * 64 + am * 16 + hi * 4 + r;
                int pcol = wn * 64 + bn * 16 + lo;
                int gi = (pcol >> 3) ^ (prow & 7);
                tP[prow * 128 + gi * 8 + (pcol & 7)] = f2b(p);
            }
    __syncthreads();
    int row = threadIdx.x >> 1;
    int cg0 = (threadIdx.x & 1) * 8;   // granule base
    u16* d = P + (size_t)(bb - batch0) * (1024 * 1024) +
             (size_t)(ti * 128 + row) * 1024 + tj * 128 + cg0 * 8;
#pragma unroll
    for (int j = 0; j < 8; j++) {
        int gi = (cg0 + j) ^ (row & 7);
        *reinterpret_cast<short8*>(d + j * 8) =
            *reinterpret_cast<const short8*>(&tP[row * 128 + gi * 8]);
    }
}

// ---------------- Kernel 4: agg = (P @ V) * rinv, V^T = xbf. 64x64 tile, K=1024.
// ell computed from the A-fragments (sum of P row) — no atomics, exact.
__global__ __launch_bounds__(256, 2) void pvgemm_kernel(const u16* __restrict__ P,
                                                        const u16* __restrict__ xbf,
                                                        u16* __restrict__ agg,
                                                        int batch0, int bmask, int bshift) {
    __shared__ u16 tA[2][4096];   // [buf][64 q rows x 64 k]  16 KB
    __shared__ u16 tB[2][4096];   // [buf][64 ch rows x 64 k] 16 KB
    int lane = threadIdx.x & 63;
    int w = threadIdx.x >> 6;
    int lo = lane & 15, hi = lane >> 4;
    int bb = batch0 + ((int)blockIdx.x & bmask);
    int rest = blockIdx.x >> bshift;
    int ct = rest & 3, rt = rest >> 2;   // 4 col-tiles x 16 row-tiles
    int brow = rt * 64, bcol = ct * 64;
    const u16* Pb  = P + (size_t)(bb - batch0) * (1024 * 1024);
    const u16* xbb = xbf + (size_t)bb * (DIM * NTOK);

    int aSrc[2], bSrc[2], dOff[2];
#pragma unroll
    for (int i = 0; i < 2; i++) {
        int idx = w * 2 + i;             // 0..7
        int rr = idx * 8 + (lane >> 3);
        int slot = (lane & 7) ^ (rr & 7);
        aSrc[i] = (brow + rr) * 1024 + slot * 8;
        bSrc[i] = (bcol + rr) * 1024 + slot * 8;
        dOff[i] = idx * 512;
    }
    f32x4 acc[4];
#pragma unroll
    for (int i = 0; i < 4; i++) acc[i] = (f32x4){0.f, 0.f, 0.f, 0.f};
    float esum = 0.f;

#pragma unroll
    for (int i = 0; i < 2; i++) {
        gl_lds(Pb  + aSrc[i], &tA[0][dOff[i]]);
        gl_lds(xbb + bSrc[i], &tB[0][dOff[i]]);
    }
    __syncthreads();

    for (int kk = 0; kk < 16; kk++) {
        int buf = kk & 1;
        if (kk < 15) {
#pragma unroll
            for (int i = 0; i < 2; i++) {
                gl_lds(Pb  + aSrc[i] + (kk + 1) * 64, &tA[buf ^ 1][dOff[i]]);
                gl_lds(xbb + bSrc[i] + (kk + 1) * 64, &tB[buf ^ 1][dOff[i]]);
            }
        }
        __builtin_amdgcn_s_setprio(1);
#pragma unroll
        for (int k0 = 0; k0 < 2; k0++) {
            int sl = ((k0 * 4 + hi) ^ (lo & 7)) * 8;
            short8 a = ld8(&tA[buf][(w * 16 + lo) * 64 + sl]);
            union { short8 v; u16 s[8]; } au; au.v = a;
            float rs = 0.f;
#pragma unroll
            for (int j = 0; j < 8; j++) rs += b2f(au.s[j]);
            esum += rs;
#pragma unroll
            for (int bn = 0; bn < 4; bn++) {
                short8 bv = ld8(&tB[buf][(bn * 16 + lo) * 64 + sl]);
                acc[bn] = mfma16(a, bv, acc[bn]);
            }
        }
        __builtin_amdgcn_s_setprio(0);
        __syncthreads();
    }

    esum += __shfl_xor(esum, 16);
    esum += __shfl_xor(esum, 32);    // lane holds ell for q-row w*16 + lo
    float rv[4];
#pragma unroll
    for (int r = 0; r < 4; r++) rv[r] = 1.f / __shfl(esum, hi * 4 + r);

    u16* tO = &tA[0][0];   // 8 KB = 64 x 64 bf16, granule-swizzled
#pragma unroll
    for (int bn = 0; bn < 4; bn++)
#pragma unroll
        for (int r = 0; r < 4; r++) {
            int orow = w * 16 + hi * 4 + r;
            int ocol = bn * 16 + lo;
            int gi = (ocol >> 3) ^ (orow & 7);
            tO[orow * 64 + gi * 8 + (ocol & 7)] = f2b(acc[bn][r] * rv[r]);
        }
    __syncthreads();
    int row = threadIdx.x >> 2;
    int cg0 = (threadIdx.x & 3) * 2;
    u16* d = agg + ((size_t)bb * NTOK + brow + row) * DIM + bcol + cg0 * 8;
#pragma unroll
    for (int j = 0; j < 2; j++) {
        int gi = (cg0 + j) ^ (row & 7);
        *reinterpret_cast<short8*>(d + j * 8) =
            *reinterpret_cast<const short8*>(&tO[row * 64 + gi * 8]);
    }
}

// ---------------- Kernel 5: FFN + residual (proven R9). 512 blocks x 32 rows,
// 8 waves = 2 rowtiles x 4 colquarters.
__global__ __launch_bounds__(512) void ffn_kernel(const u16* __restrict__ agg,
                                                  const u16* __restrict__ wbf,
                                                  const float* __restrict__ b1,
                                                  const float* __restrict__ b2,
                                                  const float* __restrict__ x,
                                                  float* __restrict__ out) {
    __shared__ u16 hl[32][264];
    int lane = threadIdx.x & 63;
    int w = threadIdx.x >> 6;
    int wr = w & 1, wc = w >> 1;
    int lo = lane & 15, hi = lane >> 4;
    int row0 = blockIdx.x * 32;
    int rw = row0 + wr * 16;
    const u16* w1b = wbf + 65536;
    const u16* w2b = wbf + 131072;

    f32x4 acc[4];
#pragma unroll
    for (int i = 0; i < 4; i++) acc[i] = (f32x4){0.f, 0.f, 0.f, 0.f};
    const u16* arow = agg + (size_t)(rw + lo) * DIM + hi * 8;
#pragma unroll
    for (int t = 0; t < 8; t++) {
        short8 a = ld8(arow + t * 32);
#pragma unroll
        for (int nf = 0; nf < 4; nf++) {
            short8 bfr = ld8(w1b + ((wc * 4 + nf) * 16 + lo) * DIM + t * 32 + hi * 8);
            acc[nf] = mfma16(a, bfr, acc[nf]);
        }
    }
#pragma unroll
    for (int nf = 0; nf < 4; nf++) {
        int f = (wc * 4 + nf) * 16 + lo;
        float bias = b1[f];
#pragma unroll
        for (int r = 0; r < 4; r++) {
            float v = acc[nf][r] + bias;
            float g = 0.5f * v * (1.f + erff(v * 0.70710678f));
            hl[wr * 16 + hi * 4 + r][f] = f2b(g);
        }
    }
    __syncthreads();

    f32x4 acc2[4];
#pragma unroll
    for (int i = 0; i < 4; i++) acc2[i] = (f32x4){0.f, 0.f, 0.f, 0.f};
#pragma unroll
    for (int t = 0; t < 8; t++) {
        short8 bh = ld8(&hl[wr * 16 + lo][t * 32 + hi * 8]);
#pragma unroll
        for (int mf = 0; mf < 4; mf++) {
            short8 a = ld8(w2b + ((wc * 4 + mf) * 16 + lo) * DIM + t * 32 + hi * 8);
            acc2[mf] = mfma16(a, bh, acc2[mf]);
        }
    }
    int bidx = row0 >> 10;
    int n = (rw & 1023) + lo;
#pragma unroll
    for (int mf = 0; mf < 4; mf++) {
#pragma unroll
        for (int r = 0; r < 4; r++) {
            int co = (wc * 4 + mf) * 16 + hi * 4 + r;
            size_t addr = (size_t)bidx * (DIM * NTOK) + (size_t)co * NTOK + n;
            out[addr] = acc2[mf][r] + b2[co] + x[addr];
        }
    }
}

extern "C" void kernel_launch(void* const* d_in, const int* in_sizes, int n_in,
                              void* d_out, int out_size, void* d_ws, size_t ws_size,
                              hipStream_t stream) {
    const float* x      = (const float*)d_in[0];
    const float* proj_w = (const float*)d_in[1];
    const float* proj_b = (const float*)d_in[2];
    const float* w1     = (const float*)d_in[3];
    const float* b1     = (const float*)d_in[4];
    const float* w2     = (const float*)d_in[5];
    const float* b2     = (const float*)d_in[6];
    float* out = (float*)d_out;

    // layout (u16): xbf | qb | wbf | agg | nodes (P reuses nodes, extends if room)
    u16* xbf   = (u16*)d_ws;
    u16* qb    = xbf + 4194304;
    u16* wbf   = qb  + 4194304;
    u16* agg   = wbf + 196608;
    u16* nodes = agg + 4194304;            // also P base
    size_t need8 = (size_t)(12779520 + 8388608) * 2;   // bytes for 8-batch P
    int nb = (ws_size >= need8) ? 8 : 4;
    int bmask = nb - 1;
    int bshift = (nb == 8) ? 3 : 2;

    pack_kernel<<<1120, 256, 0, stream>>>(x, xbf, nodes, proj_w, w1, w2, wbf);
    proj_kernel<<<1024, 256, 0, stream>>>(nodes, wbf, proj_b, qb);
    for (int h = 0; h < 16; h += nb) {
        sgemm_kernel <<<64 * nb, 256, 0, stream>>>(qb, nodes, h, bmask, bshift);
        pvgemm_kernel<<<64 * nb, 256, 0, stream>>>(nodes, xbf, agg, h, bmask, bshift);
    }
    ffn_kernel<<<512, 512, 0, stream>>>(agg, wbf, b1, b2, x, out);
}

// Round 14
// 101.144 us; speedup vs baseline: 1.2687x; 1.2687x over previous
//
#include <hip/hip_runtime.h>
#include <stdint.h>

typedef unsigned short u16;
typedef __attribute__((ext_vector_type(8))) short short8;
typedef __attribute__((ext_vector_type(4))) float f32x4;

#define NB    16
#define DIM   256
#define NTOK  1024

__device__ __forceinline__ u16 f2b(float f) {
    union { float f; uint32_t u; } v; v.f = f;
    uint32_t u = v.u;
    u += 0x7fffu + ((u >> 16) & 1u);
    return (u16)(u >> 16);
}
__device__ __forceinline__ uint32_t pack2(float a, float b) {
    return (uint32_t)f2b(a) | ((uint32_t)f2b(b) << 16);
}
__device__ __forceinline__ f32x4 mfma16(short8 a, short8 b, f32x4 c) {
    return __builtin_amdgcn_mfma_f32_16x16x32_bf16(a, b, c, 0, 0, 0);
}
__device__ __forceinline__ short8 ld8(const u16* p) {
    return *reinterpret_cast<const short8*>(p);
}
__device__ __forceinline__ void gl_lds(const u16* g, u16* l) {
    __builtin_amdgcn_global_load_lds((const __attribute__((address_space(1))) void*)g,
                                     (__attribute__((address_space(3))) void*)l, 16, 0, 0);
}

// ---------------- Kernel 1: convert 3 weight matrices to bf16 (96 blocks)
__global__ __launch_bounds__(256) void wconv_kernel(const float* __restrict__ pw,
                                                    const float* __restrict__ w1,
                                                    const float* __restrict__ w2,
                                                    u16* __restrict__ wbf) {
    int e = blockIdx.x * 2048 + threadIdx.x * 8;
    const float* s; int off;
    if (e < 65536)       { s = pw; off = e; }
    else if (e < 131072) { s = w1; off = e - 65536; }
    else                 { s = w2; off = e - 131072; }
    float4 f0 = *reinterpret_cast<const float4*>(s + off);
    float4 f1 = *reinterpret_cast<const float4*>(s + off + 4);
    ushort4 a, b;
    a.x = f2b(f0.x); a.y = f2b(f0.y); a.z = f2b(f0.z); a.w = f2b(f0.w);
    b.x = f2b(f1.x); b.y = f2b(f1.y); b.z = f2b(f1.z); b.w = f2b(f1.w);
    *reinterpret_cast<ushort4*>(wbf + e)     = a;
    *reinterpret_cast<ushort4*>(wbf + e + 4) = b;
}

// ---------------- Kernel 2: fused pack + proj. 256 blocks = 16 n-tiles x 16 batches.
// Block: loads x[b][:, n0:n0+64] (fp32, 4 chunks of 64 ch via LDS), writes xbf,
// builds swizzled [64n][256c] bf16 tile in LDS, then q = tile @ pw^T + pb -> qb.
// nodes tensor is never materialized.
__global__ __launch_bounds__(256) void packproj_kernel(const float* __restrict__ x,
                                                       u16* __restrict__ xbf,
                                                       const u16* __restrict__ wbf,
                                                       const float* __restrict__ pb,
                                                       u16* __restrict__ qb) {
    __shared__ float stage[64][68];
    __shared__ u16 tile[64 * 256];   // [n][granule gi = (c/8) ^ (n&7)]
    int tid = threadIdx.x;
    int lane = tid & 63;
    int w = tid >> 6;
    int lo = lane & 15, hi = lane >> 4;
    int b  = blockIdx.x & 15;
    int nt = blockIdx.x >> 4;
    int n0 = nt * 64;
    const float* xb = x + (size_t)b * (DIM * NTOK);
    u16* xbb = xbf + (size_t)b * (DIM * NTOK);

#pragma unroll
    for (int cc = 0; cc < 4; cc++) {
        // load 64 channels x 64 tokens (fp32) + write xbf
#pragma unroll
        for (int i = 0; i < 4; i++) {
            int idx = i * 256 + tid;
            int cl = idx >> 4, nq = idx & 15;
            float4 f = *reinterpret_cast<const float4*>(
                xb + (size_t)(cc * 64 + cl) * NTOK + n0 + nq * 4);
            stage[cl][nq * 4 + 0] = f.x;
            stage[cl][nq * 4 + 1] = f.y;
            stage[cl][nq * 4 + 2] = f.z;
            stage[cl][nq * 4 + 3] = f.w;
            ushort4 s;
            s.x = f2b(f.x); s.y = f2b(f.y); s.z = f2b(f.z); s.w = f2b(f.w);
            *reinterpret_cast<ushort4*>(xbb + (size_t)(cc * 64 + cl) * NTOK + n0 + nq * 4) = s;
        }
        __syncthreads();
        // transpose-convert into swizzled tile
#pragma unroll
        for (int j = 0; j < 2; j++) {
            int item = j * 256 + tid;
            int nl = item >> 3, g = item & 7;
            union { u16 s[8]; short8 v; } o;
#pragma unroll
            for (int k = 0; k < 8; k++) o.s[k] = f2b(stage[g * 8 + k][nl]);
            int gi = (cc * 8 + g) ^ (nl & 7);
            *reinterpret_cast<short8*>(&tile[nl * 256 + gi * 8]) = o.v;
        }
        __syncthreads();
    }

    // proj GEMM: 4 waves x 16 rows, 256 cols, K=256 from LDS tile
    f32x4 acc[16];
#pragma unroll
    for (int i = 0; i < 16; i++) acc[i] = (f32x4){0.f, 0.f, 0.f, 0.f};
    int ar = w * 16 + lo;
#pragma unroll
    for (int t = 0; t < 8; t++) {
        int gi = (t * 4 + hi) ^ (lo & 7);
        short8 a = ld8(&tile[ar * 256 + gi * 8]);
#pragma unroll
        for (int nf = 0; nf < 16; nf++) {
            short8 bfr = ld8(wbf + (nf * 16 + lo) * DIM + t * 32 + hi * 8);
            acc[nf] = mfma16(a, bfr, acc[nf]);
        }
    }
#pragma unroll
    for (int nf = 0; nf < 16; nf++) {
        int col = nf * 16 + lo;
        float bias = pb[col];
#pragma unroll
        for (int r = 0; r < 4; r++) {
            int row = n0 + w * 16 + hi * 4 + r;
            qb[(size_t)(b * NTOK + row) * DIM + col] = f2b(acc[nf][r] + bias);
        }
    }
}

// ---------------- Kernel 3: fused attention + FFN (R11 structure, fixed-offset softmax).
// 256 blocks x 256 thr; 4 waves = 2 q-tiles(32 rows) x 2 kv-halves; 32-row KV
// tiles dbuf; K/V LDS frags reused by 2 MFMAs; softmax p = exp2(s*C1 - 12)
// (exact math, no online max -> no max shuffles, no rescale).
__global__ __launch_bounds__(256, 1) void attn_ffn_kernel(const u16* __restrict__ qb,
                                                          const u16* __restrict__ xbf,
                                                          const u16* __restrict__ wbf,
                                                          const float* __restrict__ b1,
                                                          const float* __restrict__ b2,
                                                          const float* __restrict__ x,
                                                          float* __restrict__ out) {
    __shared__ u16 kls[2][2][8192];   // [stream][buf][32 rows x 256 ch]  64 KB
    __shared__ u16 vls[2][2][8192];   // [stream][buf][256 ch x 32 kv]    64 KB
    __shared__ float ellX[4][2][16];

    int lane = threadIdx.x & 63;
    int w = threadIdx.x >> 6;            // 0..3
    int qsel = w >> 1, kvh = w & 1;
    int lo = lane & 15, hi = lane >> 4;
    int b  = blockIdx.x & 15;
    int qt = blockIdx.x >> 4;            // 0..15
    int q0 = qt * 64 + qsel * 32;
    const u16* qbb = qb  + (size_t)b * (NTOK * DIM);
    const u16* xbb = xbf + (size_t)b * (DIM * NTOK);
    const u16* w1b = wbf + 65536;
    const u16* w2b = wbf + 131072;

    int kOff[8], vOff[8], kDst[8], vDst[8];
#pragma unroll
    for (int i = 0; i < 8; i++) {
        int kr = qsel * 16 + i * 2 + (lane >> 5);
        kOff[i] = kr * DIM + ((lane & 31) ^ (kr & 7)) * 8;
        kDst[i] = (qsel * 16 + i * 2) * 256;
        int vc = qsel * 128 + i * 16 + (lane >> 2);
        vOff[i] = vc * NTOK + ((lane & 3) ^ (vc & 3)) * 8;
        vDst[i] = (qsel * 128 + i * 16) * 32;
    }
    int kvbeg = kvh * 512;

    short8 bq0[8], bq1[8];
#pragma unroll
    for (int t = 0; t < 8; t++) {
        bq0[t] = ld8(qbb + (size_t)(q0 + lo) * DIM + t * 32 + hi * 8);
        bq1[t] = ld8(qbb + (size_t)(q0 + 16 + lo) * DIM + t * 32 + hi * 8);
    }

    f32x4 acc0[16], acc1[16];
#pragma unroll
    for (int i = 0; i < 16; i++) {
        acc0[i] = (f32x4){0.f, 0.f, 0.f, 0.f};
        acc1[i] = (f32x4){0.f, 0.f, 0.f, 0.f};
    }
    float ellp0 = 0.f, ellp1 = 0.f;
    const float C1 = 0.0625f * 1.44269504f;
    const float OFF = 12.0f;

#pragma unroll
    for (int i = 0; i < 8; i++) {
        gl_lds(qbb + kvbeg * DIM + kOff[i], &kls[kvh][0][kDst[i]]);
        gl_lds(xbb + kvbeg       + vOff[i], &vls[kvh][0][vDst[i]]);
    }
    __syncthreads();

    for (int tt = 0; tt < 16; tt++) {
        int buf = tt & 1;
        if (tt < 15) {
            int base = kvbeg + (tt + 1) * 32;
#pragma unroll
            for (int i = 0; i < 8; i++) {
                gl_lds(qbb + base * DIM + kOff[i], &kls[kvh][buf ^ 1][kDst[i]]);
                gl_lds(xbb + base       + vOff[i], &vls[kvh][buf ^ 1][vDst[i]]);
            }
        }
        const u16* kb = &kls[kvh][buf][0];
        const u16* vb = &vls[kvh][buf][0];

        // QK^T: 4 score frags = 2 qf x 2 kvf; K-frags read once, used twice
        f32x4 s00 = (f32x4){0.f,0.f,0.f,0.f}, s01 = (f32x4){0.f,0.f,0.f,0.f};
        f32x4 s10 = (f32x4){0.f,0.f,0.f,0.f}, s11 = (f32x4){0.f,0.f,0.f,0.f};
        __builtin_amdgcn_s_setprio(1);
#pragma unroll
        for (int t = 0; t < 8; t++) {
            int sl = ((t * 4 + hi) ^ (lo & 7)) * 8;
            short8 a0 = ld8(kb + lo * 256 + sl);
            short8 a1 = ld8(kb + (16 + lo) * 256 + sl);
            s00 = mfma16(a0, bq0[t], s00);
            s01 = mfma16(a1, bq0[t], s01);
            s10 = mfma16(a0, bq1[t], s10);
            s11 = mfma16(a1, bq1[t], s11);
        }
        __builtin_amdgcn_s_setprio(0);

        // fixed-offset softmax numerators; ell per-lane (no shuffles in-loop)
        float p00[4], p01[4], p10[4], p11[4];
#pragma unroll
        for (int r = 0; r < 4; r++) {
            p00[r] = exp2f(s00[r] * C1 - OFF);
            p01[r] = exp2f(s01[r] * C1 - OFF);
            p10[r] = exp2f(s10[r] * C1 - OFF);
            p11[r] = exp2f(s11[r] * C1 - OFF);
            ellp0 += p00[r] + p01[r];
            ellp1 += p10[r] + p11[r];
        }

        // redistribute P -> B-frag, per qf (8 shfl each)
        short8 pfrag0, pfrag1;
        {
            uint32_t pl0 = pack2(p00[0], p00[1]), ph0 = pack2(p00[2], p00[3]);
            uint32_t pl1 = pack2(p01[0], p01[1]), ph1 = pack2(p01[2], p01[3]);
            int srcA = ((hi & 1) << 5) | lo;
            int srcB = srcA + 16;
            uint32_t w0a = __shfl(pl0, srcA), w0b = __shfl(pl1, srcA);
            uint32_t w1a = __shfl(ph0, srcA), w1b = __shfl(ph1, srcA);
            uint32_t w2a = __shfl(pl0, srcB), w2b = __shfl(pl1, srcB);
            uint32_t w3a = __shfl(ph0, srcB), w3b = __shfl(ph1, srcB);
            bool sel = (hi >= 2);
            union { uint32_t u[4]; short8 v; } pu;
            pu.u[0] = sel ? w0b : w0a;
            pu.u[1] = sel ? w1b : w1a;
            pu.u[2] = sel ? w2b : w2a;
            pu.u[3] = sel ? w3b : w3a;
            pfrag0 = pu.v;
        }
        {
            uint32_t pl0 = pack2(p10[0], p10[1]), ph0 = pack2(p10[2], p10[3]);
            uint32_t pl1 = pack2(p11[0], p11[1]), ph1 = pack2(p11[2], p11[3]);
            int srcA = ((hi & 1) << 5) | lo;
            int srcB = srcA + 16;
            uint32_t w0a = __shfl(pl0, srcA), w0b = __shfl(pl1, srcA);
            uint32_t w1a = __shfl(ph0, srcA), w1b = __shfl(ph1, srcA);
            uint32_t w2a = __shfl(pl0, srcB), w2b = __shfl(pl1, srcB);
            uint32_t w3a = __shfl(ph0, srcB), w3b = __shfl(ph1, srcB);
            bool sel = (hi >= 2);
            union { uint32_t u[4]; short8 v; } pu;
            pu.u[0] = sel ? w0b : w0a;
            pu.u[1] = sel ? w1b : w1a;
            pu.u[2] = sel ? w2b : w2a;
            pu.u[3] = sel ? w3b : w3a;
            pfrag1 = pu.v;
        }

        // PV: V-frag read once, used by both qf
        int vsl = (hi ^ (lo & 3)) * 8;
        __builtin_amdgcn_s_setprio(1);
#pragma unroll
        for (int mf = 0; mf < 16; mf++) {
            short8 a = ld8(vb + (mf * 16 + lo) * 32 + vsl);
            acc0[mf] = mfma16(a, pfrag0, acc0[mf]);
            acc1[mf] = mfma16(a, pfrag1, acc1[mf]);
        }
        __builtin_amdgcn_s_setprio(0);
        __syncthreads();
    }

    // ---- ell reduce + cross-half combine (no rescale — shared fixed offset) ----
    float e0 = ellp0;
    e0 += __shfl_xor(e0, 16); e0 += __shfl_xor(e0, 32);
    float e1 = ellp1;
    e1 += __shfl_xor(e1, 16); e1 += __shfl_xor(e1, 32);
    if (lane < 16) { ellX[w][0][lane] = e0; ellX[w][1][lane] = e1; }
    __syncthreads();
    float rinv0 = 1.f / (e0 + ellX[w ^ 1][0][lo]);
    float rinv1 = 1.f / (e1 + ellX[w ^ 1][1][lo]);

    char* pbase = (char*)kls;   // 64 KB giveaway scratch
    if (kvh == 0) {
#pragma unroll
        for (int j = 0; j < 8; j++) {
            int byt = (w * 2 + 0) * 8192 + lo * 512 + ((j * 64 + hi * 16) ^ ((lo & 7) << 4));
            *reinterpret_cast<f32x4*>(pbase + byt) = acc0[8 + j];
            int byt1 = (w * 2 + 1) * 8192 + lo * 512 + ((j * 64 + hi * 16) ^ ((lo & 7) << 4));
            *reinterpret_cast<f32x4*>(pbase + byt1) = acc1[8 + j];
        }
    } else {
#pragma unroll
        for (int j = 0; j < 8; j++) {
            int byt = (w * 2 + 0) * 8192 + lo * 512 + ((j * 64 + hi * 16) ^ ((lo & 7) << 4));
            *reinterpret_cast<f32x4*>(pbase + byt) = acc0[j];
            int byt1 = (w * 2 + 1) * 8192 + lo * 512 + ((j * 64 + hi * 16) ^ ((lo & 7) << 4));
            *reinterpret_cast<f32x4*>(pbase + byt1) = acc1[j];
        }
    }
    __syncthreads();
    char* abase = (char*)vls;   // agg [64][256] bf16, 16B-granule ^ (row&7)
    if (kvh == 0) {
#pragma unroll
        for (int j = 0; j < 8; j++) {
            int pb0 = ((w ^ 1) * 2 + 0) * 8192 + lo * 512 + ((j * 64 + hi * 16) ^ ((lo & 7) << 4));
            f32x4 o = *reinterpret_cast<const f32x4*>(pbase + pb0);
            uint32_t lo32 = pack2((acc0[j][0] + o[0]) * rinv0, (acc0[j][1] + o[1]) * rinv0);
            uint32_t hi32 = pack2((acc0[j][2] + o[2]) * rinv0, (acc0[j][3] + o[3]) * rinv0);
            int slot = j * 2 + (hi >> 1);
            int arow = qsel * 32 + lo;
            int byteA = arow * 512 + ((slot ^ (lo & 7)) * 16) + (hi & 1) * 8;
            *reinterpret_cast<uint32_t*>(abase + byteA)     = lo32;
            *reinterpret_cast<uint32_t*>(abase + byteA + 4) = hi32;
            int pb1 = ((w ^ 1) * 2 + 1) * 8192 + lo * 512 + ((j * 64 + hi * 16) ^ ((lo & 7) << 4));
            f32x4 o1 = *reinterpret_cast<const f32x4*>(pbase + pb1);
            uint32_t lo32b = pack2((acc1[j][0] + o1[0]) * rinv1, (acc1[j][1] + o1[1]) * rinv1);
            uint32_t hi32b = pack2((acc1[j][2] + o1[2]) * rinv1, (acc1[j][3] + o1[3]) * rinv1);
            int arow1 = qsel * 32 + 16 + lo;
            int byteB = arow1 * 512 + ((slot ^ (lo & 7)) * 16) + (hi & 1) * 8;
            *reinterpret_cast<uint32_t*>(abase + byteB)     = lo32b;
            *reinterpret_cast<uint32_t*>(abase + byteB + 4) = hi32b;
        }
    } else {
#pragma unroll
        for (int j = 0; j < 8; j++) {
            int pb0 = ((w ^ 1) * 2 + 0) * 8192 + lo * 512 + ((j * 64 + hi * 16) ^ ((lo & 7) << 4));
            f32x4 o = *reinterpret_cast<const f32x4*>(pbase + pb0);
            uint32_t lo32 = pack2((acc0[8 + j][0] + o[0]) * rinv0, (acc0[8 + j][1] + o[1]) * rinv0);
            uint32_t hi32 = pack2((acc0[8 + j][2] + o[2]) * rinv0, (acc0[8 + j][3] + o[3]) * rinv0);
            int slot = 16 + j * 2 + (hi >> 1);
            int arow = qsel * 32 + lo;
            int byteA = arow * 512 + ((slot ^ (lo & 7)) * 16) + (hi & 1) * 8;
            *reinterpret_cast<uint32_t*>(abase + byteA)     = lo32;
            *reinterpret_cast<uint32_t*>(abase + byteA + 4) = hi32;
            int pb1 = ((w ^ 1) * 2 + 1) * 8192 + lo * 512 + ((j * 64 + hi * 16) ^ ((lo & 7) << 4));
            f32x4 o1 = *reinterpret_cast<const f32x4*>(pbase + pb1);
            uint32_t lo32b = pack2((acc1[8 + j][0] + o1[0]) * rinv1, (acc1[8 + j][1] + o1[1]) * rinv1);
            uint32_t hi32b = pack2((acc1[8 + j][2] + o1[2]) * rinv1, (acc1[8 + j][3] + o1[3]) * rinv1);
            int arow1 = qsel * 32 + 16 + lo;
            int byteB = arow1 * 512 + ((slot ^ (lo & 7)) * 16) + (hi & 1) * 8;
            *reinterpret_cast<uint32_t*>(abase + byteB)     = lo32b;
            *reinterpret_cast<uint32_t*>(abase + byteB + 4) = hi32b;
        }
    }
    __syncthreads();

    // ---- FFN: 4 waves = 2 rowhalves(32) x 2 colhalves(128); weight frags
    // reused across the 2 row-frags.
    int rh = w >> 1, chh = w & 1;
    f32x4 f1a[8], f1b[8];
#pragma unroll
    for (int i = 0; i < 8; i++) {
        f1a[i] = (f32x4){0.f, 0.f, 0.f, 0.f};
        f1b[i] = (f32x4){0.f, 0.f, 0.f, 0.f};
    }
#pragma unroll
    for (int t = 0; t < 8; t++) {
        int g = ((t * 4 + hi) ^ (lo & 7)) * 16;
        short8 aA = *reinterpret_cast<const short8*>(abase + (rh * 32 + lo) * 512 + g);
        short8 aB = *reinterpret_cast<const short8*>(abase + (rh * 32 + 16 + lo) * 512 + g);
#pragma unroll
        for (int nf = 0; nf < 8; nf++) {
            short8 bfr = ld8(w1b + ((chh * 8 + nf) * 16 + lo) * DIM + t * 32 + hi * 8);
            f1a[nf] = mfma16(aA, bfr, f1a[nf]);
            f1b[nf] = mfma16(aB, bfr, f1b[nf]);
        }
    }
    u16* hl = (u16*)kls;   // [64][264]
#pragma unroll
    for (int nf = 0; nf < 8; nf++) {
        int f = (chh * 8 + nf) * 16 + lo;
        float bias = b1[f];
#pragma unroll
        for (int r = 0; r < 4; r++) {
            float va = f1a[nf][r] + bias;
            float vb2 = f1b[nf][r] + bias;
            float ga = 0.5f * va * (1.f + erff(va * 0.70710678f));
            float gb = 0.5f * vb2 * (1.f + erff(vb2 * 0.70710678f));
            hl[(rh * 32 + hi * 4 + r) * 264 + f]      = f2b(ga);
            hl[(rh * 32 + 16 + hi * 4 + r) * 264 + f] = f2b(gb);
        }
    }
    __syncthreads();

    f32x4 f2a[8], f2b_[8];
#pragma unroll
    for (int i = 0; i < 8; i++) {
        f2a[i] = (f32x4){0.f, 0.f, 0.f, 0.f};
        f2b_[i] = (f32x4){0.f, 0.f, 0.f, 0.f};
    }
#pragma unroll
    for (int t = 0; t < 8; t++) {
        short8 hA = ld8(hl + (rh * 32 + lo) * 264 + t * 32 + hi * 8);
        short8 hB = ld8(hl + (rh * 32 + 16 + lo) * 264 + t * 32 + hi * 8);
#pragma unroll
        for (int mf = 0; mf < 8; mf++) {
            short8 a2 = ld8(w2b + ((chh * 8 + mf) * 16 + lo) * DIM + t * 32 + hi * 8);
            f2a[mf] = mfma16(a2, hA, f2a[mf]);
            f2b_[mf] = mfma16(a2, hB, f2b_[mf]);
        }
    }
    int nA = qt * 64 + rh * 32 + lo;
    int nB = nA + 16;
#pragma unroll
    for (int mf = 0; mf < 8; mf++) {
#pragma unroll
        for (int r = 0; r < 4; r++) {
            int co = (chh * 8 + mf) * 16 + hi * 4 + r;
            size_t rowb = (size_t)b * (DIM * NTOK) + (size_t)co * NTOK;
            out[rowb + nA] = f2a[mf][r] + b2[co] + x[rowb + nA];
            out[rowb + nB] = f2b_[mf][r] + b2[co] + x[rowb + nB];
        }
    }
}

extern "C" void kernel_launch(void* const* d_in, const int* in_sizes, int n_in,
                              void* d_out, int out_size, void* d_ws, size_t ws_size,
                              hipStream_t stream) {
    const float* x      = (const float*)d_in[0];
    const float* proj_w = (const float*)d_in[1];
    const float* proj_b = (const float*)d_in[2];
    const float* w1     = (const float*)d_in[3];
    const float* b1     = (const float*)d_in[4];
    const float* w2     = (const float*)d_in[5];
    const float* b2     = (const float*)d_in[6];
    float* out = (float*)d_out;

    u16* xbf = (u16*)d_ws;
    u16* qb  = xbf + 4194304;
    u16* wbf = qb  + 4194304;

    wconv_kernel   <<<96,   256, 0, stream>>>(proj_w, w1, w2, wbf);
    packproj_kernel<<<256,  256, 0, stream>>>(x, xbf, wbf, proj_b, qb);
    attn_ffn_kernel<<<256,  256, 0, stream>>>(qb, xbf, wbf, b1, b2, x, out);
}